// Round 1
// baseline (8440.100 us; speedup 1.0000x reference)
//
#include <hip/hip_runtime.h>

#define C 128            // hidden/out channels
#define INCH 64          // input channels

__device__ __forceinline__ float silu_f(float v) {
    return v / (1.0f + __expf(-v));
}

// ---------- preprocessing ----------

__global__ void fill_ones_k(float* p, int n) {
    int i = blockIdx.x * blockDim.x + threadIdx.x;
    if (i < n) p[i] = 1.0f;
}

__global__ void deg_scatter_k(const int* __restrict__ dst, const float* __restrict__ w,
                              float* deg, int E) {
    int e = blockIdx.x * blockDim.x + threadIdx.x;
    if (e < E) atomicAdd(&deg[dst[e]], w[e]);
}

__global__ void make_dinv_k(float* deg, int n) {
    int i = blockIdx.x * blockDim.x + threadIdx.x;
    if (i < n) deg[i] = rsqrtf(deg[i]);   // deg >= 1 (self-loop) so always > 0
}

__global__ void make_norm_k(const int* __restrict__ src, const int* __restrict__ dst,
                            const float* __restrict__ w, const float* __restrict__ dinv,
                            float* __restrict__ norm, int E) {
    int e = blockIdx.x * blockDim.x + threadIdx.x;
    if (e < E) norm[e] = dinv[src[e]] * w[e] * dinv[dst[e]];
}

// ---------- GEMM: H = act(x) @ W ; AGG = H * dinv^2 (self-loop init) ----------
// act(x) = ACT ? silu(x + bias) : x   (bias = previous layer's bias)
// 256 threads/block, 32 rows x 128 cols per block, 4x4 register tile/thread.
// NOTE: x may alias AGG (in-place): each block reads only its own 32 rows into
// LDS before the barrier, and only overwrites those same rows in the epilogue.

template<int K, bool ACT>
__launch_bounds__(256, 2)
__global__ void gemm_k(const float* x, const float* __restrict__ W,
                       const float* __restrict__ bias, const float* __restrict__ dinv,
                       float* H, float* AGG, int N) {
    __shared__ float Ws[K][C];
    __shared__ float Xs[32][K];
    const int tid = threadIdx.x;
    const int r0 = blockIdx.x * 32;

    // load W (K*C floats) vectorized
    for (int i4 = tid; i4 < (K * C) / 4; i4 += 256) {
        *(float4*)&Ws[(i4 * 4) / C][(i4 * 4) % C] = *(const float4*)&W[i4 * 4];
    }
    // load X tile (32*K floats), apply previous layer's activation on the fly
    for (int i4 = tid; i4 < (32 * K) / 4; i4 += 256) {
        int base = i4 * 4;
        int r = base / K, k = base % K;
        float4 v = make_float4(0.f, 0.f, 0.f, 0.f);
        if (r0 + r < N) {
            v = *(const float4*)&x[(size_t)(r0 + r) * K + k];
            if (ACT) {
                v.x = silu_f(v.x + bias[k + 0]);
                v.y = silu_f(v.y + bias[k + 1]);
                v.z = silu_f(v.z + bias[k + 2]);
                v.w = silu_f(v.w + bias[k + 3]);
            }
        }
        *(float4*)&Xs[r][k] = v;
    }
    __syncthreads();

    const int cg = (tid & 31) * 4;   // col base (0..124)
    const int rg = (tid >> 5) * 4;   // row base (0..28)
    float acc[4][4] = {};
    for (int k = 0; k < K; ++k) {
        float4 wv = *(const float4*)&Ws[k][cg];
        float xr0 = Xs[rg + 0][k];
        float xr1 = Xs[rg + 1][k];
        float xr2 = Xs[rg + 2][k];
        float xr3 = Xs[rg + 3][k];
        acc[0][0] = fmaf(xr0, wv.x, acc[0][0]); acc[0][1] = fmaf(xr0, wv.y, acc[0][1]);
        acc[0][2] = fmaf(xr0, wv.z, acc[0][2]); acc[0][3] = fmaf(xr0, wv.w, acc[0][3]);
        acc[1][0] = fmaf(xr1, wv.x, acc[1][0]); acc[1][1] = fmaf(xr1, wv.y, acc[1][1]);
        acc[1][2] = fmaf(xr1, wv.z, acc[1][2]); acc[1][3] = fmaf(xr1, wv.w, acc[1][3]);
        acc[2][0] = fmaf(xr2, wv.x, acc[2][0]); acc[2][1] = fmaf(xr2, wv.y, acc[2][1]);
        acc[2][2] = fmaf(xr2, wv.z, acc[2][2]); acc[2][3] = fmaf(xr2, wv.w, acc[2][3]);
        acc[3][0] = fmaf(xr3, wv.x, acc[3][0]); acc[3][1] = fmaf(xr3, wv.y, acc[3][1]);
        acc[3][2] = fmaf(xr3, wv.z, acc[3][2]); acc[3][3] = fmaf(xr3, wv.w, acc[3][3]);
    }

    // epilogue: write H and AGG = H * dinv^2 (self-loop contribution)
    #pragma unroll
    for (int i = 0; i < 4; ++i) {
        int r = r0 + rg + i;
        if (r < N) {
            float di = dinv[r];
            float d2 = di * di;
            float4 h = make_float4(acc[i][0], acc[i][1], acc[i][2], acc[i][3]);
            *(float4*)&H[(size_t)r * C + cg] = h;
            float4 a = make_float4(h.x * d2, h.y * d2, h.z * d2, h.w * d2);
            *(float4*)&AGG[(size_t)r * C + cg] = a;
        }
    }
}

// ---------- edge scatter: AGG[dst] += H[src] * norm ----------
// one thread per (edge, float4-chunk): 32 threads cover an edge's 128 channels

__global__ void edge_scatter_k(const float* __restrict__ H, const int* __restrict__ src,
                               const int* __restrict__ dst, const float* __restrict__ norm,
                               float* AGG, int E) {
    long long idx = (long long)blockIdx.x * blockDim.x + threadIdx.x;
    if (idx >= (long long)E * 32) return;
    int e = (int)(idx >> 5);
    int q = (int)(idx & 31);
    int s = src[e];
    int d = dst[e];
    float nm = norm[e];
    float4 v = *(const float4*)(H + (size_t)s * C + q * 4);
    float* ap = AGG + (size_t)d * C + q * 4;
    atomicAdd(ap + 0, v.x * nm);
    atomicAdd(ap + 1, v.y * nm);
    atomicAdd(ap + 2, v.z * nm);
    atomicAdd(ap + 3, v.w * nm);
}

// ---------- final: out[c] = mean_i silu(AGG[i][c] + b3[c]) ----------

__global__ void zero_out_k(float* out, int n) {
    int i = threadIdx.x;
    if (i < n) out[i] = 0.f;
}

#define MP_ROWS 512
__global__ void mean_pool_k(const float* __restrict__ AGG, const float* __restrict__ b,
                            float* out, int N) {
    int c = threadIdx.x;             // 128 threads = 128 channels
    int r0 = blockIdx.x * MP_ROWS;
    float bc = b[c];
    float acc = 0.f;
    for (int i = 0; i < MP_ROWS; ++i) {
        int r = r0 + i;
        if (r < N) acc += silu_f(AGG[(size_t)r * C + c] + bc);
    }
    atomicAdd(&out[c], acc * (1.0f / N));
}

// ---------- launch ----------

extern "C" void kernel_launch(void* const* d_in, const int* in_sizes, int n_in,
                              void* d_out, int out_size, void* d_ws, size_t ws_size,
                              hipStream_t stream) {
    const float* x  = (const float*)d_in[0];
    const int*   ei = (const int*)d_in[1];
    const float* ew = (const float*)d_in[2];
    const float* W1 = (const float*)d_in[3];
    const float* b1 = (const float*)d_in[4];
    const float* W2 = (const float*)d_in[5];
    const float* b2 = (const float*)d_in[6];
    const float* W3 = (const float*)d_in[7];
    const float* b3 = (const float*)d_in[8];
    float* out = (float*)d_out;

    const int N = in_sizes[0] / INCH;
    const int E = in_sizes[1] / 2;
    const int* src = ei;
    const int* dst = ei + E;

    char* ws = (char*)d_ws;
    size_t off = 0;
    auto alloc = [&](size_t bytes) -> void* {
        void* p = ws + off;
        off += (bytes + 255) & ~(size_t)255;
        return p;
    };
    float* H    = (float*)alloc((size_t)N * C * sizeof(float));
    float* AGG  = (float*)alloc((size_t)N * C * sizeof(float));
    float* norm = (float*)alloc((size_t)E * sizeof(float));
    float* dinv = (float*)alloc((size_t)N * sizeof(float));
    (void)ws_size;

    const int nb = (N + 255) / 256;
    const int eb = (E + 255) / 256;

    // normalization: deg = 1 (self-loop) + sum_in w ; dinv = rsqrt(deg); norm per edge
    fill_ones_k<<<nb, 256, 0, stream>>>(dinv, N);
    deg_scatter_k<<<eb, 256, 0, stream>>>(dst, ew, dinv, E);
    make_dinv_k<<<nb, 256, 0, stream>>>(dinv, N);
    make_norm_k<<<eb, 256, 0, stream>>>(src, dst, ew, dinv, norm, E);

    const int gb = (N + 31) / 32;
    const long long st = (long long)E * 32;
    const int sb = (int)((st + 255) / 256);

    // layer 1: x(64) -> H/AGG, scatter
    gemm_k<INCH, false><<<gb, 256, 0, stream>>>(x, W1, nullptr, dinv, H, AGG, N);
    edge_scatter_k<<<sb, 256, 0, stream>>>(H, src, dst, norm, AGG, E);
    // layer 2: silu(AGG+b1)(128) -> H/AGG (in-place read/overwrite of AGG), scatter
    gemm_k<C, true><<<gb, 256, 0, stream>>>(AGG, W2, b1, dinv, H, AGG, N);
    edge_scatter_k<<<sb, 256, 0, stream>>>(H, src, dst, norm, AGG, E);
    // layer 3
    gemm_k<C, true><<<gb, 256, 0, stream>>>(AGG, W3, b2, dinv, H, AGG, N);
    edge_scatter_k<<<sb, 256, 0, stream>>>(H, src, dst, norm, AGG, E);

    // mean pool with final bias+silu
    zero_out_k<<<1, 128, 0, stream>>>(out, out_size);
    mean_pool_k<<<(N + MP_ROWS - 1) / MP_ROWS, 128, 0, stream>>>(AGG, b3, out, N);
}

// Round 2
// 925.662 us; speedup vs baseline: 9.1179x; 9.1179x over previous
//
#include <hip/hip_runtime.h>

#define C 128            // hidden/out channels
#define INCH 64          // input channels

__device__ __forceinline__ float silu_f(float v) {
    return v / (1.0f + __expf(-v));
}

// ---------- preprocessing ----------

// deg=1 (self loop weight), counts=0, cursor=0
__global__ void init_k(float* deg, int* counts, int* cursor, int n) {
    int i = blockIdx.x * blockDim.x + threadIdx.x;
    if (i < n) { deg[i] = 1.0f; counts[i] = 0; cursor[i] = 0; }
}

__global__ void hist_deg_k(const int* __restrict__ dst, const float* __restrict__ w,
                           float* deg, int* counts, int E) {
    int e = blockIdx.x * blockDim.x + threadIdx.x;
    if (e < E) {
        int d = dst[e];
        atomicAdd(&deg[d], w[e]);
        atomicAdd(&counts[d], 1);
    }
}

__global__ void make_dinv_k(float* deg, int n) {
    int i = blockIdx.x * blockDim.x + threadIdx.x;
    if (i < n) deg[i] = rsqrtf(deg[i]);   // deg >= 1 (self-loop) so always > 0
}

// ---------- exclusive scan of counts -> rowptr (1024 elems / block) ----------

#define SCAN_T 256
#define SCAN_E 1024

__global__ void scan1_k(const int* __restrict__ counts, int* rowptr, int* bsums, int N) {
    __shared__ int s[SCAN_T];
    int t = threadIdx.x;
    int base = blockIdx.x * SCAN_E + t * 4;
    int v[4];
    #pragma unroll
    for (int j = 0; j < 4; ++j) { int i = base + j; v[j] = (i < N) ? counts[i] : 0; }
    int sum = v[0] + v[1] + v[2] + v[3];
    s[t] = sum; __syncthreads();
    for (int off = 1; off < SCAN_T; off <<= 1) {
        int y = (t >= off) ? s[t - off] : 0;
        __syncthreads();
        s[t] += y;
        __syncthreads();
    }
    int incl = s[t];
    int excl = incl - sum;
    if (t == SCAN_T - 1) bsums[blockIdx.x] = incl;
    int run = excl;
    #pragma unroll
    for (int j = 0; j < 4; ++j) { int i = base + j; if (i < N) rowptr[i] = run; run += v[j]; }
}

__global__ void scan2_k(int* bsums, int nb) {
    __shared__ int s[128];
    int t = threadIdx.x;
    int v = (t < nb) ? bsums[t] : 0;
    s[t] = v; __syncthreads();
    for (int off = 1; off < 128; off <<= 1) {
        int y = (t >= off) ? s[t - off] : 0;
        __syncthreads();
        s[t] += y;
        __syncthreads();
    }
    if (t < nb) bsums[t] = s[t] - v;   // exclusive block offsets
}

__global__ void scan3_k(int* rowptr, const int* __restrict__ bsums, int N, int E) {
    int i = blockIdx.x * blockDim.x + threadIdx.x;
    if (i < N) rowptr[i] += bsums[i >> 10];
    if (i == 0) rowptr[N] = E;
}

// ---------- CSR fill: bucket edges by dst, fuse norm computation ----------

__global__ void fill_csr_k(const int* __restrict__ src, const int* __restrict__ dst,
                           const float* __restrict__ w, const float* __restrict__ dinv,
                           const int* __restrict__ rowptr, int* cursor,
                           int* esrc, float* enorm, int E) {
    int e = blockIdx.x * blockDim.x + threadIdx.x;
    if (e >= E) return;
    int s = src[e], d = dst[e];
    float nm = dinv[s] * w[e] * dinv[d];
    int pos = rowptr[d] + atomicAdd(&cursor[d], 1);
    esrc[pos] = s;
    enorm[pos] = nm;
}

// ---------- GEMM: H = act(x) @ W ----------
// act(x) = ACT ? silu(x + bias) : x   (bias = previous layer's bias)
// 256 threads/block, 32 rows x 128 cols per block, 4x4 register tile/thread.

template<int K, bool ACT>
__launch_bounds__(256, 2)
__global__ void gemm_k(const float* __restrict__ x, const float* __restrict__ W,
                       const float* __restrict__ bias, float* __restrict__ H, int N) {
    __shared__ float Ws[K][C];
    __shared__ float Xs[32][K];
    const int tid = threadIdx.x;
    const int r0 = blockIdx.x * 32;

    for (int i4 = tid; i4 < (K * C) / 4; i4 += 256) {
        *(float4*)&Ws[(i4 * 4) / C][(i4 * 4) % C] = *(const float4*)&W[i4 * 4];
    }
    for (int i4 = tid; i4 < (32 * K) / 4; i4 += 256) {
        int base = i4 * 4;
        int r = base / K, k = base % K;
        float4 v = make_float4(0.f, 0.f, 0.f, 0.f);
        if (r0 + r < N) {
            v = *(const float4*)&x[(size_t)(r0 + r) * K + k];
            if (ACT) {
                v.x = silu_f(v.x + bias[k + 0]);
                v.y = silu_f(v.y + bias[k + 1]);
                v.z = silu_f(v.z + bias[k + 2]);
                v.w = silu_f(v.w + bias[k + 3]);
            }
        }
        *(float4*)&Xs[r][k] = v;
    }
    __syncthreads();

    const int cg = (tid & 31) * 4;   // col base (0..124)
    const int rg = (tid >> 5) * 4;   // row base (0..28)
    float acc[4][4] = {};
    for (int k = 0; k < K; ++k) {
        float4 wv = *(const float4*)&Ws[k][cg];
        float xr0 = Xs[rg + 0][k];
        float xr1 = Xs[rg + 1][k];
        float xr2 = Xs[rg + 2][k];
        float xr3 = Xs[rg + 3][k];
        acc[0][0] = fmaf(xr0, wv.x, acc[0][0]); acc[0][1] = fmaf(xr0, wv.y, acc[0][1]);
        acc[0][2] = fmaf(xr0, wv.z, acc[0][2]); acc[0][3] = fmaf(xr0, wv.w, acc[0][3]);
        acc[1][0] = fmaf(xr1, wv.x, acc[1][0]); acc[1][1] = fmaf(xr1, wv.y, acc[1][1]);
        acc[1][2] = fmaf(xr1, wv.z, acc[1][2]); acc[1][3] = fmaf(xr1, wv.w, acc[1][3]);
        acc[2][0] = fmaf(xr2, wv.x, acc[2][0]); acc[2][1] = fmaf(xr2, wv.y, acc[2][1]);
        acc[2][2] = fmaf(xr2, wv.z, acc[2][2]); acc[2][3] = fmaf(xr2, wv.w, acc[2][3]);
        acc[3][0] = fmaf(xr3, wv.x, acc[3][0]); acc[3][1] = fmaf(xr3, wv.y, acc[3][1]);
        acc[3][2] = fmaf(xr3, wv.z, acc[3][2]); acc[3][3] = fmaf(xr3, wv.w, acc[3][3]);
    }

    #pragma unroll
    for (int i = 0; i < 4; ++i) {
        int r = r0 + rg + i;
        if (r < N) {
            *(float4*)&H[(size_t)r * C + cg] =
                make_float4(acc[i][0], acc[i][1], acc[i][2], acc[i][3]);
        }
    }
}

// ---------- aggregation (gather): AGG[d] = H[d]*dinv[d]^2 + sum_e H[src_e]*norm_e ----------
// one 64-lane wave per dst node; lane owns 2 channels (float2) -> full 128-ch row in regs

__launch_bounds__(256)
__global__ void agg_gather_k(const float* __restrict__ H, const int* __restrict__ esrc,
                             const float* __restrict__ enorm, const int* __restrict__ rowptr,
                             const float* __restrict__ dinv, float* __restrict__ AGG, int N) {
    int wave = (int)((blockIdx.x * (long long)blockDim.x + threadIdx.x) >> 6);
    int lane = threadIdx.x & 63;
    if (wave >= N) return;
    const int d = wave;
    const int c = lane * 2;

    float di = dinv[d];
    float d2 = di * di;
    float2 acc = *(const float2*)&H[(size_t)d * C + c];
    acc.x *= d2; acc.y *= d2;

    int i   = rowptr[d];
    int end = rowptr[d + 1];
    for (; i + 1 < end; i += 2) {
        int s0 = esrc[i], s1 = esrc[i + 1];
        float n0 = enorm[i], n1 = enorm[i + 1];
        float2 v0 = *(const float2*)&H[(size_t)s0 * C + c];
        float2 v1 = *(const float2*)&H[(size_t)s1 * C + c];
        acc.x = fmaf(v0.x, n0, acc.x); acc.y = fmaf(v0.y, n0, acc.y);
        acc.x = fmaf(v1.x, n1, acc.x); acc.y = fmaf(v1.y, n1, acc.y);
    }
    if (i < end) {
        int s0 = esrc[i];
        float n0 = enorm[i];
        float2 v0 = *(const float2*)&H[(size_t)s0 * C + c];
        acc.x = fmaf(v0.x, n0, acc.x); acc.y = fmaf(v0.y, n0, acc.y);
    }
    *(float2*)&AGG[(size_t)d * C + c] = acc;
}

// ---------- final: out[c] = mean_i silu(AGG[i][c] + b3[c]) ----------

__global__ void zero_out_k(float* out, int n) {
    int i = threadIdx.x;
    if (i < n) out[i] = 0.f;
}

#define MP_ROWS 512
__global__ void mean_pool_k(const float* __restrict__ AGG, const float* __restrict__ b,
                            float* out, int N) {
    int c = threadIdx.x;             // 128 threads = 128 channels
    int r0 = blockIdx.x * MP_ROWS;
    float bc = b[c];
    float acc = 0.f;
    for (int i = 0; i < MP_ROWS; ++i) {
        int r = r0 + i;
        if (r < N) acc += silu_f(AGG[(size_t)r * C + c] + bc);
    }
    atomicAdd(&out[c], acc * (1.0f / N));
}

// ---------- launch ----------

extern "C" void kernel_launch(void* const* d_in, const int* in_sizes, int n_in,
                              void* d_out, int out_size, void* d_ws, size_t ws_size,
                              hipStream_t stream) {
    const float* x  = (const float*)d_in[0];
    const int*   ei = (const int*)d_in[1];
    const float* ew = (const float*)d_in[2];
    const float* W1 = (const float*)d_in[3];
    const float* b1 = (const float*)d_in[4];
    const float* W2 = (const float*)d_in[5];
    const float* b2 = (const float*)d_in[6];
    const float* W3 = (const float*)d_in[7];
    const float* b3 = (const float*)d_in[8];
    float* out = (float*)d_out;

    const int N = in_sizes[0] / INCH;
    const int E = in_sizes[1] / 2;
    const int* src = ei;
    const int* dst = ei + E;

    char* ws = (char*)d_ws;
    size_t off = 0;
    auto alloc = [&](size_t bytes) -> void* {
        void* p = ws + off;
        off += (bytes + 255) & ~(size_t)255;
        return p;
    };
    float* H      = (float*)alloc((size_t)N * C * sizeof(float));
    float* AGG    = (float*)alloc((size_t)N * C * sizeof(float));
    int*   esrc   = (int*)  alloc((size_t)E * sizeof(int));
    float* enorm  = (float*)alloc((size_t)E * sizeof(float));
    int*   rowptr = (int*)  alloc((size_t)(N + 1) * sizeof(int));
    int*   counts = (int*)  alloc((size_t)N * sizeof(int));
    int*   cursor = (int*)  alloc((size_t)N * sizeof(int));
    float* dinv   = (float*)alloc((size_t)N * sizeof(float));
    int*   bsums  = (int*)  alloc(256 * sizeof(int));
    (void)ws_size;

    const int nb = (N + 255) / 256;
    const int eb = (E + 255) / 256;
    const int sbk = (N + SCAN_E - 1) / SCAN_E;   // scan blocks (<=128)

    // normalization + CSR build
    init_k<<<nb, 256, 0, stream>>>(dinv, counts, cursor, N);
    hist_deg_k<<<eb, 256, 0, stream>>>(dst, ew, dinv, counts, E);
    make_dinv_k<<<nb, 256, 0, stream>>>(dinv, N);
    scan1_k<<<sbk, SCAN_T, 0, stream>>>(counts, rowptr, bsums, N);
    scan2_k<<<1, 128, 0, stream>>>(bsums, sbk);
    scan3_k<<<nb, 256, 0, stream>>>(rowptr, bsums, N, E);
    fill_csr_k<<<eb, 256, 0, stream>>>(src, dst, ew, dinv, rowptr, cursor, esrc, enorm, E);

    const int gb = (N + 31) / 32;              // gemm blocks
    const int ab = (N + 3) / 4;                // agg blocks (4 waves/block)

    // layer 1: x(64) -> H, aggregate -> AGG
    gemm_k<INCH, false><<<gb, 256, 0, stream>>>(x, W1, nullptr, H, N);
    agg_gather_k<<<ab, 256, 0, stream>>>(H, esrc, enorm, rowptr, dinv, AGG, N);
    // layer 2: silu(AGG+b1)(128) -> H, aggregate
    gemm_k<C, true><<<gb, 256, 0, stream>>>(AGG, W2, b1, H, N);
    agg_gather_k<<<ab, 256, 0, stream>>>(H, esrc, enorm, rowptr, dinv, AGG, N);
    // layer 3
    gemm_k<C, true><<<gb, 256, 0, stream>>>(AGG, W3, b2, H, N);
    agg_gather_k<<<ab, 256, 0, stream>>>(H, esrc, enorm, rowptr, dinv, AGG, N);

    // mean pool with final bias+silu
    zero_out_k<<<1, 128, 0, stream>>>(out, out_size);
    mean_pool_k<<<(N + MP_ROWS - 1) / MP_ROWS, 128, 0, stream>>>(AGG, b3, out, N);
}

// Round 3
// 836.493 us; speedup vs baseline: 10.0899x; 1.1066x over previous
//
#include <hip/hip_runtime.h>

#define C 128            // hidden/out channels
#define INCH 64          // input channels

__device__ __forceinline__ float silu_f(float v) {
    return v / (1.0f + __expf(-v));
}

// ---------- preprocessing ----------

// deg=1 (self loop weight), counts=0, cursor=0
__global__ void init_k(float* deg, int* counts, int* cursor, int n) {
    int i = blockIdx.x * blockDim.x + threadIdx.x;
    if (i < n) { deg[i] = 1.0f; counts[i] = 0; cursor[i] = 0; }
}

__global__ void hist_deg_k(const int* __restrict__ dst, const float* __restrict__ w,
                           float* deg, int* counts, int E) {
    int e = blockIdx.x * blockDim.x + threadIdx.x;
    if (e < E) {
        int d = dst[e];
        atomicAdd(&deg[d], w[e]);
        atomicAdd(&counts[d], 1);
    }
}

__global__ void make_dinv_k(float* deg, int n) {
    int i = blockIdx.x * blockDim.x + threadIdx.x;
    if (i < n) deg[i] = rsqrtf(deg[i]);   // deg >= 1 (self-loop) so always > 0
}

// ---------- exclusive scan of counts -> rowptr (1024 elems / block) ----------

#define SCAN_T 256
#define SCAN_E 1024

__global__ void scan1_k(const int* __restrict__ counts, int* rowptr, int* bsums, int N) {
    __shared__ int s[SCAN_T];
    int t = threadIdx.x;
    int base = blockIdx.x * SCAN_E + t * 4;
    int v[4];
    #pragma unroll
    for (int j = 0; j < 4; ++j) { int i = base + j; v[j] = (i < N) ? counts[i] : 0; }
    int sum = v[0] + v[1] + v[2] + v[3];
    s[t] = sum; __syncthreads();
    for (int off = 1; off < SCAN_T; off <<= 1) {
        int y = (t >= off) ? s[t - off] : 0;
        __syncthreads();
        s[t] += y;
        __syncthreads();
    }
    int incl = s[t];
    int excl = incl - sum;
    if (t == SCAN_T - 1) bsums[blockIdx.x] = incl;
    int run = excl;
    #pragma unroll
    for (int j = 0; j < 4; ++j) { int i = base + j; if (i < N) rowptr[i] = run; run += v[j]; }
}

__global__ void scan2_k(int* bsums, int nb) {
    __shared__ int s[128];
    int t = threadIdx.x;
    int v = (t < nb) ? bsums[t] : 0;
    s[t] = v; __syncthreads();
    for (int off = 1; off < 128; off <<= 1) {
        int y = (t >= off) ? s[t - off] : 0;
        __syncthreads();
        s[t] += y;
        __syncthreads();
    }
    if (t < nb) bsums[t] = s[t] - v;   // exclusive block offsets
}

__global__ void scan3_k(int* rowptr, const int* __restrict__ bsums, int N, int E) {
    int i = blockIdx.x * blockDim.x + threadIdx.x;
    if (i < N) rowptr[i] += bsums[i >> 10];
    if (i == 0) rowptr[N] = E;
}

// ---------- CSR fill: bucket edges by dst, fuse norm computation ----------

__global__ void fill_csr_k(const int* __restrict__ src, const int* __restrict__ dst,
                           const float* __restrict__ w, const float* __restrict__ dinv,
                           const int* __restrict__ rowptr, int* cursor,
                           int* esrc, float* enorm, int E) {
    int e = blockIdx.x * blockDim.x + threadIdx.x;
    if (e >= E) return;
    int s = src[e], d = dst[e];
    float nm = dinv[s] * w[e] * dinv[d];
    int pos = rowptr[d] + atomicAdd(&cursor[d], 1);
    esrc[pos] = s;
    enorm[pos] = nm;
}

// ---------- GEMM: H = act(x) @ W ----------
// act(x) = ACT ? silu(x + bias) : x   (bias = previous layer's bias)

template<int K, bool ACT>
__launch_bounds__(256, 2)
__global__ void gemm_k(const float* __restrict__ x, const float* __restrict__ W,
                       const float* __restrict__ bias, float* __restrict__ H, int N) {
    __shared__ float Ws[K][C];
    __shared__ float Xs[32][K];
    const int tid = threadIdx.x;
    const int r0 = blockIdx.x * 32;

    for (int i4 = tid; i4 < (K * C) / 4; i4 += 256) {
        *(float4*)&Ws[(i4 * 4) / C][(i4 * 4) % C] = *(const float4*)&W[i4 * 4];
    }
    for (int i4 = tid; i4 < (32 * K) / 4; i4 += 256) {
        int base = i4 * 4;
        int r = base / K, k = base % K;
        float4 v = make_float4(0.f, 0.f, 0.f, 0.f);
        if (r0 + r < N) {
            v = *(const float4*)&x[(size_t)(r0 + r) * K + k];
            if (ACT) {
                v.x = silu_f(v.x + bias[k + 0]);
                v.y = silu_f(v.y + bias[k + 1]);
                v.z = silu_f(v.z + bias[k + 2]);
                v.w = silu_f(v.w + bias[k + 3]);
            }
        }
        *(float4*)&Xs[r][k] = v;
    }
    __syncthreads();

    const int cg = (tid & 31) * 4;   // col base (0..124)
    const int rg = (tid >> 5) * 4;   // row base (0..28)
    float acc[4][4] = {};
    for (int k = 0; k < K; ++k) {
        float4 wv = *(const float4*)&Ws[k][cg];
        float xr0 = Xs[rg + 0][k];
        float xr1 = Xs[rg + 1][k];
        float xr2 = Xs[rg + 2][k];
        float xr3 = Xs[rg + 3][k];
        acc[0][0] = fmaf(xr0, wv.x, acc[0][0]); acc[0][1] = fmaf(xr0, wv.y, acc[0][1]);
        acc[0][2] = fmaf(xr0, wv.z, acc[0][2]); acc[0][3] = fmaf(xr0, wv.w, acc[0][3]);
        acc[1][0] = fmaf(xr1, wv.x, acc[1][0]); acc[1][1] = fmaf(xr1, wv.y, acc[1][1]);
        acc[1][2] = fmaf(xr1, wv.z, acc[1][2]); acc[1][3] = fmaf(xr1, wv.w, acc[1][3]);
        acc[2][0] = fmaf(xr2, wv.x, acc[2][0]); acc[2][1] = fmaf(xr2, wv.y, acc[2][1]);
        acc[2][2] = fmaf(xr2, wv.z, acc[2][2]); acc[2][3] = fmaf(xr2, wv.w, acc[2][3]);
        acc[3][0] = fmaf(xr3, wv.x, acc[3][0]); acc[3][1] = fmaf(xr3, wv.y, acc[3][1]);
        acc[3][2] = fmaf(xr3, wv.z, acc[3][2]); acc[3][3] = fmaf(xr3, wv.w, acc[3][3]);
    }

    #pragma unroll
    for (int i = 0; i < 4; ++i) {
        int r = r0 + rg + i;
        if (r < N) {
            *(float4*)&H[(size_t)r * C + cg] =
                make_float4(acc[i][0], acc[i][1], acc[i][2], acc[i][3]);
        }
    }
}

// ---------- aggregation (gather): acc[d] = H[d]*dinv[d]^2 + sum_e H[src_e]*norm_e ----------
// one 64-lane wave per dst node; lane owns 2 channels (float2).
// Edge metadata loaded cooperatively (64 edges / coalesced 256B) and shfl-broadcast.
// POOL=false: write acc -> AGG[d].
// POOL=true : silu(acc + bias) then block-reduce 4 waves -> partial[block][128] (layer 3).

template<bool POOL>
__launch_bounds__(256)
__global__ void agg_gather_k(const float* __restrict__ H, const int* __restrict__ esrc,
                             const float* __restrict__ enorm, const int* __restrict__ rowptr,
                             const float* __restrict__ dinv, const float* __restrict__ bias,
                             float* __restrict__ outbuf, int N) {
    const int wid  = threadIdx.x >> 6;
    const int lane = threadIdx.x & 63;
    const int d = blockIdx.x * 4 + wid;
    const bool active = d < N;
    const int c = lane * 2;

    float2 a0 = make_float2(0.f, 0.f);
    float2 a1 = make_float2(0.f, 0.f);
    int beg = 0, end = 0;
    if (active) {
        float di = dinv[d];
        float d2 = di * di;
        float2 h = *(const float2*)&H[(size_t)d * C + c];
        a0.x = h.x * d2; a0.y = h.y * d2;
        beg = rowptr[d]; end = rowptr[d + 1];
    }
    while (beg < end) {                       // wave-uniform bounds
        int cnt = end - beg; if (cnt > 64) cnt = 64;
        int es = 0; float nm = 0.f;
        if (lane < cnt) { es = esrc[beg + lane]; nm = enorm[beg + lane]; }
        int j = 0;
        for (; j + 1 < cnt; j += 2) {
            int   s0 = __shfl(es, j);     float n0 = __shfl(nm, j);
            int   s1 = __shfl(es, j + 1); float n1 = __shfl(nm, j + 1);
            float2 v0 = *(const float2*)&H[(size_t)s0 * C + c];
            float2 v1 = *(const float2*)&H[(size_t)s1 * C + c];
            a0.x = fmaf(v0.x, n0, a0.x); a0.y = fmaf(v0.y, n0, a0.y);
            a1.x = fmaf(v1.x, n1, a1.x); a1.y = fmaf(v1.y, n1, a1.y);
        }
        if (j < cnt) {
            int s0 = __shfl(es, j); float n0 = __shfl(nm, j);
            float2 v0 = *(const float2*)&H[(size_t)s0 * C + c];
            a0.x = fmaf(v0.x, n0, a0.x); a0.y = fmaf(v0.y, n0, a0.y);
        }
        beg += cnt;
    }
    float2 acc = make_float2(a0.x + a1.x, a0.y + a1.y);

    if (!POOL) {
        if (active) *(float2*)&outbuf[(size_t)d * C + c] = acc;
    } else {
        __shared__ float2 red[4][64];
        float2 v = make_float2(0.f, 0.f);
        if (active) {
            v.x = silu_f(acc.x + bias[c]);
            v.y = silu_f(acc.y + bias[c + 1]);
        }
        red[wid][lane] = v;
        __syncthreads();
        if (threadIdx.x < 64) {
            float2 t0 = red[0][lane], t1 = red[1][lane];
            float2 t2 = red[2][lane], t3 = red[3][lane];
            float2 t = make_float2(t0.x + t1.x + t2.x + t3.x,
                                   t0.y + t1.y + t2.y + t3.y);
            *(float2*)&outbuf[(size_t)blockIdx.x * C + c] = t;
        }
    }
}

// ---------- 2-stage reduce of partials -> out ----------

__global__ void reduce1_k(const float* __restrict__ partial, float* __restrict__ p2,
                          int NB, int chunk) {
    int t = threadIdx.x;                      // 128 = channel
    int r0 = blockIdx.x * chunk;
    int r1 = r0 + chunk; if (r1 > NB) r1 = NB;
    float s = 0.f;
    for (int r = r0; r < r1; ++r) s += partial[(size_t)r * C + t];
    p2[(size_t)blockIdx.x * C + t] = s;
}

__global__ void reduce2_k(const float* __restrict__ p2, float* __restrict__ out,
                          int R1, float inv_n) {
    int t = threadIdx.x;                      // 128 = channel
    float s = 0.f;
    for (int r = 0; r < R1; ++r) s += p2[(size_t)r * C + t];
    out[t] = s * inv_n;
}

// ---------- launch ----------

extern "C" void kernel_launch(void* const* d_in, const int* in_sizes, int n_in,
                              void* d_out, int out_size, void* d_ws, size_t ws_size,
                              hipStream_t stream) {
    const float* x  = (const float*)d_in[0];
    const int*   ei = (const int*)d_in[1];
    const float* ew = (const float*)d_in[2];
    const float* W1 = (const float*)d_in[3];
    const float* b1 = (const float*)d_in[4];
    const float* W2 = (const float*)d_in[5];
    const float* b2 = (const float*)d_in[6];
    const float* W3 = (const float*)d_in[7];
    const float* b3 = (const float*)d_in[8];
    float* out = (float*)d_out;

    const int N = in_sizes[0] / INCH;
    const int E = in_sizes[1] / 2;
    const int* src = ei;
    const int* dst = ei + E;

    char* ws = (char*)d_ws;
    size_t off = 0;
    auto alloc = [&](size_t bytes) -> void* {
        void* p = ws + off;
        off += (bytes + 255) & ~(size_t)255;
        return p;
    };
    float* H      = (float*)alloc((size_t)N * C * sizeof(float));
    float* AGG    = (float*)alloc((size_t)N * C * sizeof(float));
    int*   esrc   = (int*)  alloc((size_t)E * sizeof(int));
    float* enorm  = (float*)alloc((size_t)E * sizeof(float));
    int*   rowptr = (int*)  alloc((size_t)(N + 1) * sizeof(int));
    int*   counts = (int*)  alloc((size_t)N * sizeof(int));
    int*   cursor = (int*)  alloc((size_t)N * sizeof(int));
    float* dinv   = (float*)alloc((size_t)N * sizeof(float));
    int*   bsums  = (int*)  alloc(256 * sizeof(int));
    (void)ws_size;

    const int nb = (N + 255) / 256;
    const int eb = (E + 255) / 256;
    const int sbk = (N + SCAN_E - 1) / SCAN_E;   // scan blocks (<=128)

    // normalization + CSR build
    init_k<<<nb, 256, 0, stream>>>(dinv, counts, cursor, N);
    hist_deg_k<<<eb, 256, 0, stream>>>(dst, ew, dinv, counts, E);
    make_dinv_k<<<nb, 256, 0, stream>>>(dinv, N);
    scan1_k<<<sbk, SCAN_T, 0, stream>>>(counts, rowptr, bsums, N);
    scan2_k<<<1, 128, 0, stream>>>(bsums, sbk);
    scan3_k<<<nb, 256, 0, stream>>>(rowptr, bsums, N, E);
    fill_csr_k<<<eb, 256, 0, stream>>>(src, dst, ew, dinv, rowptr, cursor, esrc, enorm, E);

    const int gb  = (N + 31) / 32;             // gemm blocks
    const int ab  = (N + 3) / 4;               // agg blocks (4 waves/block)

    // layer 1: x(64) -> H, aggregate -> AGG
    gemm_k<INCH, false><<<gb, 256, 0, stream>>>(x, W1, nullptr, H, N);
    agg_gather_k<false><<<ab, 256, 0, stream>>>(H, esrc, enorm, rowptr, dinv, nullptr, AGG, N);
    // layer 2: silu(AGG+b1)(128) -> H, aggregate
    gemm_k<C, true><<<gb, 256, 0, stream>>>(AGG, W2, b1, H, N);
    agg_gather_k<false><<<ab, 256, 0, stream>>>(H, esrc, enorm, rowptr, dinv, nullptr, AGG, N);
    // layer 3: gemm -> H, fused aggregate + bias + silu + block-pool -> partials (alias AGG)
    gemm_k<C, true><<<gb, 256, 0, stream>>>(AGG, W3, b2, H, N);
    float* partial = AGG;                      // AGG free in POOL mode; 25000*128 floats fit
    agg_gather_k<true><<<ab, 256, 0, stream>>>(H, esrc, enorm, rowptr, dinv, b3, partial, N);

    // 2-stage mean reduce: partial[ab][128] -> p2[R1][128] -> out[128]
    const int R1 = 100;
    const int chunk = (ab + R1 - 1) / R1;
    float* p2 = (float*)cursor;                // cursor (N ints) free after fill_csr
    reduce1_k<<<R1, 128, 0, stream>>>(partial, p2, ab, chunk);
    reduce2_k<<<1, 128, 0, stream>>>(p2, out, R1, 1.0f / (float)N);
}